// Round 5
// baseline (429.020 us; speedup 1.0000x reference)
//
#include <hip/hip_runtime.h>

// TransformerBlock: B=2, S=2048, D=1024, H=16, dh=64, FFN=4096.
// Round 5: split-K flash attention (2 key-halves per q-tile -> 8192 balanced
// waves) + partial-combine kernel. Swapped-operand lane-local softmax kept.

typedef __attribute__((ext_vector_type(8))) short s16x8;
typedef __attribute__((ext_vector_type(4))) float f32x4;
typedef unsigned short u16;
typedef unsigned int u32;

#define DEV static __device__ __forceinline__
#define MFMA16 __builtin_amdgcn_mfma_f32_16x16x32_bf16
#define GLOAD_LDS16(gp, lp)                                         \
  __builtin_amdgcn_global_load_lds(                                 \
      (const __attribute__((address_space(1))) void*)(gp),          \
      (__attribute__((address_space(3))) void*)(lp), 16, 0, 0)

DEV u16 f2bf(float f) {
  union { float f; unsigned u; } c; c.f = f;
  unsigned u = c.u;
  u += 0x7fff + ((u >> 16) & 1);   // RNE
  return (u16)(u >> 16);
}

DEV float bf2f(u16 v) {
  union { u32 u; float f; } c; c.u = (u32)v << 16;
  return c.f;
}

DEV u32 cvtpk(float lo, float hi) {  // packed f32x2 -> bf16x2 (RNE)
  u32 r;
  asm("v_cvt_pk_bf16_f32 %0, %1, %2" : "=v"(r) : "v"(lo), "v"(hi));
  return r;
}

DEV float gelu_tanh(float v) {
  const float c0 = 0.7978845608028654f;  // sqrt(2/pi)
  float u = c0 * (v + 0.044715f * v * v * v);
  return 0.5f * v * (1.0f + tanhf(u));
}

// ---------- transpose + convert: W fp32 [K,N] -> Wt bf16 [N,K] -------------
__global__ __launch_bounds__(256) void tconv_kernel(
    const float* __restrict__ W, u16* __restrict__ Wt, int K, int N) {
  __shared__ u16 T[64][80];
  const int t = threadIdx.x;
  const int n0 = blockIdx.x * 64, k0 = blockIdx.y * 64;
  const int kr = t >> 4, nc = (t & 15) * 4;
#pragma unroll
  for (int p = 0; p < 4; ++p) {
    const int k = p * 16 + kr;
    float4 v = *(const float4*)(W + (size_t)(k0 + k) * N + n0 + nc);
    T[nc + 0][k] = f2bf(v.x);
    T[nc + 1][k] = f2bf(v.y);
    T[nc + 2][k] = f2bf(v.z);
    T[nc + 3][k] = f2bf(v.w);
  }
  __syncthreads();
  const int nr = t >> 2, kc = (t & 3) * 16;
  *(s16x8*)(Wt + (size_t)(n0 + nr) * K + k0 + kc) = *(const s16x8*)&T[nr][kc];
  *(s16x8*)(Wt + (size_t)(n0 + nr) * K + k0 + kc + 8) =
      *(const s16x8*)&T[nr][kc + 8];
}

// ---------------- LayerNorm: fp32 [rows,1024] -> bf16 [rows,1024] ----------
__global__ __launch_bounds__(256) void ln_kernel(
    const float* __restrict__ x, const float* __restrict__ g,
    const float* __restrict__ b, u16* __restrict__ out) {
  const int row = blockIdx.x;
  const int t = threadIdx.x;
  const float* xr = x + (size_t)row * 1024;
  float4 v = *(const float4*)(xr + t * 4);
  float s = v.x + v.y + v.z + v.w;
  float ss = v.x * v.x + v.y * v.y + v.z * v.z + v.w * v.w;
#pragma unroll
  for (int off = 1; off < 64; off <<= 1) {
    s += __shfl_xor(s, off);
    ss += __shfl_xor(ss, off);
  }
  __shared__ float sb[4], ssb[4];
  const int w = t >> 6;
  if ((t & 63) == 0) { sb[w] = s; ssb[w] = ss; }
  __syncthreads();
  s = sb[0] + sb[1] + sb[2] + sb[3];
  ss = ssb[0] + ssb[1] + ssb[2] + ssb[3];
  const float mean = s * (1.0f / 1024.0f);
  const float var = ss * (1.0f / 1024.0f) - mean * mean;
  const float rstd = rsqrtf(var + 1e-5f);
  const int c = t * 4;
  ushort4 o;
  o.x = f2bf(g[c + 0] * ((v.x - mean) * rstd) + b[c + 0]);
  o.y = f2bf(g[c + 1] * ((v.y - mean) * rstd) + b[c + 1]);
  o.z = f2bf(g[c + 2] * ((v.z - mean) * rstd) + b[c + 2]);
  o.w = f2bf(g[c + 3] * ((v.w - mean) * rstd) + b[c + 3]);
  *(ushort4*)(out + (size_t)row * 1024 + c) = o;
}

// ---------------- GEMM: C[M,N] = A(bf16)[M,K] @ Bt(bf16)[N,K]^T ------------
template <int EPI>
__global__ __launch_bounds__(256) void gemm_kernel(
    const u16* __restrict__ A, const u16* __restrict__ Bt,
    const float* __restrict__ bias, const float* __restrict__ res,
    void* __restrict__ Cv, int M, int N, int K) {
  __shared__ __align__(16) u16 Al[128][32];
  __shared__ __align__(16) u16 Bl[128][32];
  const int t = threadIdx.x;
  const int lane = t & 63, w = t >> 6;
  const int wm = (w >> 1) * 64, wn = (w & 1) * 64;
  const int bm = blockIdx.y * 128, bn = blockIdx.x * 128;
  const int lr = lane & 15, lg = lane >> 4;
  const int srow = lane >> 2, scol = (lane & 3) * 8;
  f32x4 acc[4][4] = {};

  for (int kt = 0; kt < K; kt += 32) {
    __syncthreads();
#pragma unroll
    for (int p = 0; p < 2; ++p) {
      const int r0 = (w * 2 + p) * 16;
      GLOAD_LDS16(A + (size_t)(bm + r0 + srow) * K + kt + scol, &Al[r0][0]);
      GLOAD_LDS16(Bt + (size_t)(bn + r0 + srow) * K + kt + scol, &Bl[r0][0]);
    }
    __syncthreads();
    s16x8 af[4], bf[4];
#pragma unroll
    for (int i = 0; i < 4; ++i) {
      af[i] = *(const s16x8*)&Al[wm + i * 16 + lr][lg * 8];
      bf[i] = *(const s16x8*)&Bl[wn + i * 16 + lr][lg * 8];
    }
#pragma unroll
    for (int i = 0; i < 4; ++i)
#pragma unroll
      for (int j = 0; j < 4; ++j)
        acc[i][j] = MFMA16(af[i], bf[j], acc[i][j], 0, 0, 0);
  }

#pragma unroll
  for (int i = 0; i < 4; ++i) {
    const int row = bm + wm + i * 16 + lg * 4;  // + e
#pragma unroll
    for (int j = 0; j < 4; ++j) {
      const int col = bn + wn + j * 16 + lr;
      if (EPI == 0) {
        const int bb = row >> 11, sloc = row & 2047;
        const int which = col >> 10, n = col & 1023;
        const int hh = n >> 6, dd = n & 63;
        u16* qbuf = (u16*)Cv;
        if (which == 2) {  // V transposed [bh][64][2048]
          ushort4 o;
          o.x = f2bf(acc[i][j][0]); o.y = f2bf(acc[i][j][1]);
          o.z = f2bf(acc[i][j][2]); o.w = f2bf(acc[i][j][3]);
          *(ushort4*)(qbuf + 8388608 +
                      (size_t)((bb * 16 + hh) * 64 + dd) * 2048 + sloc) = o;
        } else {
          // q pre-scaled by (1/8)*log2(e) so attention runs in exp2 space
          const float sc = (which == 0) ? 0.18033688011112042f : 1.0f;
          u16* dst = qbuf + (size_t)which * 4194304 +
                     ((size_t)(bb * 16 + hh) * 2048 + sloc) * 64 + dd;
#pragma unroll
          for (int e = 0; e < 4; ++e) dst[(size_t)e * 64] = f2bf(acc[i][j][e] * sc);
        }
      } else if (EPI == 1) {
        float* C = (float*)Cv;
        const float bs = bias[col];
#pragma unroll
        for (int e = 0; e < 4; ++e)
          C[(size_t)(row + e) * N + col] =
              acc[i][j][e] + bs + res[(size_t)(row + e) * N + col];
      } else {
        u16* C = (u16*)Cv;
        const float bs = bias[col];
#pragma unroll
        for (int e = 0; e < 4; ++e)
          C[(size_t)(row + e) * N + col] = f2bf(gelu_tanh(acc[i][j][e] + bs));
      }
    }
  }
}

// ---------------- Flash attention: swapped-operand, split-K ----------------
// Qg,Kg: [32][2048][64] bf16 (q pre-scaled to exp2 space); Vt: [32][64][2048].
// Block = 1 wave; blockIdx.x = t*2 + h: q-tile t (16 rows), key-half h.
// Partial (unnormalized O bf16, m, l) written per (t,h); combined later.
struct AttnChain {
  s16x8 aq0, aq1;   // Q[q=lr][d=lg*8+j], halves d<32 / d>=32
  f32x4 acco[4];    // O[q=lr][d = c*16 + lg*4 + e]
  float m, l;       // running max / denom for row q=lr (log2 space)
};

template <bool DIAG>
DEV void attn_tile(AttnChain& st, int k0, int qs, const u16* Kbase,
                   const u16* Vbase, u32* Prow, int lr, int lg, int swz) {
  // K fragments: K[key=k0+s*16+lr][d]
  s16x8 kb0[4], kb1[4];
#pragma unroll
  for (int s = 0; s < 4; ++s) {
    const u16* kp = Kbase + (size_t)(k0 + s * 16 + lr) * 64 + lg * 8;
    kb0[s] = *(const s16x8*)kp;
    kb1[s] = *(const s16x8*)(kp + 32);
  }
  // S^T = K Q^T: lane holds S[key=k0+s*16+lg*4+e][q=qs+lr]
  f32x4 sc[4];
#pragma unroll
  for (int s = 0; s < 4; ++s) {
    f32x4 a = {};
    a = MFMA16(kb0[s], st.aq0, a, 0, 0, 0);
    a = MFMA16(kb1[s], st.aq1, a, 0, 0, 0);
    sc[s] = a;
  }
  // V fragments in flight during softmax: V^T[d=c*16+lr][key]
  s16x8 vb0[4], vb1[4];
#pragma unroll
  for (int c = 0; c < 4; ++c) {
    const u16* vp = Vbase + (size_t)(c * 16 + lr) * 2048 + k0 + lg * 8;
    vb0[c] = *(const s16x8*)vp;
    vb1[c] = *(const s16x8*)(vp + 32);
  }
  if (DIAG) {
#pragma unroll
    for (int s = 0; s < 4; ++s)
#pragma unroll
      for (int e = 0; e < 4; ++e)
        if (k0 + s * 16 + lg * 4 + e > qs + lr) sc[s][e] = -INFINITY;
  }
  // row max: in-lane 16 + 2 shfl (across lg partition)
  float mt = fmaxf(fmaxf(sc[0][0], sc[0][1]), fmaxf(sc[0][2], sc[0][3]));
#pragma unroll
  for (int s = 1; s < 4; ++s)
    mt = fmaxf(mt, fmaxf(fmaxf(sc[s][0], sc[s][1]), fmaxf(sc[s][2], sc[s][3])));
  mt = fmaxf(mt, __shfl_xor(mt, 16));
  mt = fmaxf(mt, __shfl_xor(mt, 32));
  const float mn = fmaxf(st.m, mt);
  const float sf = exp2f(st.m - mn);
  float p[4][4];
  float rs = 0.f;
#pragma unroll
  for (int s = 0; s < 4; ++s)
#pragma unroll
    for (int e = 0; e < 4; ++e) {
      p[s][e] = exp2f(sc[s][e] - mn);
      rs += p[s][e];
    }
  rs += __shfl_xor(rs, 16);
  rs += __shfl_xor(rs, 32);
  st.l = st.l * sf + rs;
  st.m = mn;
  // pack P -> LDS (swizzled), re-read as MFMA B-frag P[q=lr][k=lg*8+j]
#pragma unroll
  for (int s = 0; s < 4; ++s) {
    uint2 wv;
    wv.x = cvtpk(p[s][0], p[s][1]);
    wv.y = cvtpk(p[s][2], p[s][3]);
    *(uint2*)&Prow[(s * 8 + lg * 2) ^ swz] = wv;
  }
  const s16x8 pa0 = *(const s16x8*)&Prow[(lg * 4) ^ swz];
  const s16x8 pa1 = *(const s16x8*)&Prow[(16 + lg * 4) ^ swz];
  // rescale + O^T += V^T P^T  (stays in q=lr space)
#pragma unroll
  for (int c = 0; c < 4; ++c) {
    f32x4 a = st.acco[c];
    a[0] *= sf; a[1] *= sf; a[2] *= sf; a[3] *= sf;
    st.acco[c] = a;
  }
#pragma unroll
  for (int c = 0; c < 4; ++c) {
    st.acco[c] = MFMA16(vb0[c], pa0, st.acco[c], 0, 0, 0);
    st.acco[c] = MFMA16(vb1[c], pa1, st.acco[c], 0, 0, 0);
  }
}

DEV void attn_init(AttnChain& st, const u16* Qbase, int qs, int lr, int lg) {
  const u16* qp = Qbase + (size_t)(qs + lr) * 64 + lg * 8;
  st.aq0 = *(const s16x8*)qp;
  st.aq1 = *(const s16x8*)(qp + 32);
  st.m = -INFINITY;
  st.l = 0.f;
#pragma unroll
  for (int c = 0; c < 4; ++c) st.acco[c] = f32x4{};
}

__global__ __launch_bounds__(64, 4) void attn_kernel(
    const u16* __restrict__ Qg, const u16* __restrict__ Kg,
    const u16* __restrict__ Vt, u16* __restrict__ pO,
    float* __restrict__ pml) {
  __shared__ __align__(16) u32 P32[16][32];
  const int lane = threadIdx.x & 63;
  const int tx = blockIdx.x, bh = blockIdx.y;
  const int t = tx >> 1, h = tx & 1;
  const int lr = lane & 15, lg = lane >> 4;
  const int swz = (lr & 7) << 2;
  const int qs = t * 16;
  const int nt = t / 4 + 1;          // 64-key tiles for this q-tile
  const int mid = nt >> 1;
  const int ktb = h ? mid : 0;
  const int kte = h ? nt : mid;      // h=1 owns the diagonal tile (nt-1)
  const size_t baseK = (size_t)bh * 2048 * 64;
  const size_t baseV = (size_t)bh * 64 * 2048;
  const u16* Kb = Kg + baseK;
  const u16* Vb = Vt + baseV;
  u32* Pr = &P32[lr][0];

  AttnChain A;
  attn_init(A, Qg + baseK, qs, lr, lg);

  for (int kt = ktb; kt < kte - h; ++kt)
    attn_tile<false>(A, kt * 64, qs, Kb, Vb, Pr, lr, lg, swz);
  if (h) attn_tile<true>(A, (nt - 1) * 64, qs, Kb, Vb, Pr, lr, lg, swz);

  // write partial: O bf16 [16][64], m/l fp32 [16]+[16]
  const int p = (((bh << 7) | t) << 1) | h;
  u16* po = pO + (size_t)p * 1024 + lr * 64 + lg * 4;
#pragma unroll
  for (int c = 0; c < 4; ++c) {
    uint2 o;
    o.x = cvtpk(A.acco[c][0], A.acco[c][1]);
    o.y = cvtpk(A.acco[c][2], A.acco[c][3]);
    *(uint2*)(po + c * 16) = o;
  }
  if (lane < 16) {
    pml[p * 32 + lr] = A.m;
    pml[p * 32 + 16 + lr] = A.l;
  }
}

// ---------------- combine two key-half partials -> ctx bf16 ----------------
__global__ __launch_bounds__(64) void attn_combine(
    const u16* __restrict__ pO, const float* __restrict__ pml,
    u16* __restrict__ ctx) {
  const int t = blockIdx.x, bh = blockIdx.y;
  const int lane = threadIdx.x & 63;
  const int p0 = (((bh << 7) | t) << 1);
  const u16* o0 = pO + (size_t)p0 * 1024;
  const u16* o1 = o0 + 1024;
  const int rbase = (lane >> 4) << 2, col = (lane & 15) * 4;
  const int bb = bh >> 4, hh = bh & 15;
#pragma unroll
  for (int rr = 0; rr < 4; ++rr) {
    const int r = rbase + rr;
    const float m0 = pml[p0 * 32 + r], l0 = pml[p0 * 32 + 16 + r];
    const float m1 = pml[p0 * 32 + 32 + r], l1 = pml[p0 * 32 + 48 + r];
    const float M = fmaxf(m0, m1);
    const float w0 = exp2f(m0 - M), w1 = exp2f(m1 - M);
    const float inv = 1.0f / (l0 * w0 + l1 * w1);
    ushort4 a = *(const ushort4*)(o0 + r * 64 + col);
    ushort4 b = *(const ushort4*)(o1 + r * 64 + col);
    ushort4 o;
    o.x = f2bf((bf2f(a.x) * w0 + bf2f(b.x) * w1) * inv);
    o.y = f2bf((bf2f(a.y) * w0 + bf2f(b.y) * w1) * inv);
    o.z = f2bf((bf2f(a.z) * w0 + bf2f(b.z) * w1) * inv);
    o.w = f2bf((bf2f(a.w) * w0 + bf2f(b.w) * w1) * inv);
    const int q = t * 16 + r;
    *(ushort4*)(ctx + (size_t)(bb * 2048 + q) * 1024 + hh * 64 + col) = o;
  }
}

// ---------------------------------------------------------------------------
extern "C" void kernel_launch(void* const* d_in, const int* in_sizes, int n_in,
                              void* d_out, int out_size, void* d_ws,
                              size_t ws_size, hipStream_t stream) {
  const float* x  = (const float*)d_in[0];
  const float* wq = (const float*)d_in[1];
  const float* wk = (const float*)d_in[2];
  const float* wv = (const float*)d_in[3];
  const float* wo = (const float*)d_in[4];
  const float* bo = (const float*)d_in[5];
  const float* w1 = (const float*)d_in[6];
  const float* b1 = (const float*)d_in[7];
  const float* w2 = (const float*)d_in[8];
  const float* b2 = (const float*)d_in[9];
  const float* g1 = (const float*)d_in[10];
  const float* s1 = (const float*)d_in[11];
  const float* g2 = (const float*)d_in[12];
  const float* s2 = (const float*)d_in[13];
  float* out = (float*)d_out;

  // ws layout (MB), lifetimes ordered so aliases never overlap live ranges:
  //  0-8   hb (LN1 out; dead after QKV GEMM)       [gb aliases 0-32 in FFN]
  //  8-32  qbuf q|k|vt (dead after attn)
  //  32-40 ctxb
  //  40-46 qkvw (dead after QKV GEMM)
  //  40-56 pO partials bf16 (attn->combine)  /  x2 fp32 (proj onward)
  //  56-57 pml (attn->combine)
  //  57-65 h2b
  //  65-67 wot | 67-75 w1t | 75-83 w2t
  const size_t MB = (size_t)1 << 20;
  char* p = (char*)d_ws;
  u16* hb    = (u16*)(p + 0 * MB);
  u16* qbuf  = (u16*)(p + 8 * MB);
  u16* ctxb  = (u16*)(p + 32 * MB);
  u16* qkvw  = (u16*)(p + 40 * MB);
  u16* pO    = (u16*)(p + 40 * MB);
  float* x2  = (float*)(p + 40 * MB);
  float* pml = (float*)(p + 56 * MB);
  u16* h2b   = (u16*)(p + 57 * MB);
  u16* wot   = (u16*)(p + 65 * MB);
  u16* w1t   = (u16*)(p + 67 * MB);
  u16* w2t   = (u16*)(p + 75 * MB);
  u16* gb    = (u16*)(p + 0 * MB);

  const dim3 blk(256);
  tconv_kernel<<<dim3(16, 16), blk, 0, stream>>>(wq, qkvw, 1024, 1024);
  tconv_kernel<<<dim3(16, 16), blk, 0, stream>>>(wk, qkvw + 1048576, 1024, 1024);
  tconv_kernel<<<dim3(16, 16), blk, 0, stream>>>(wv, qkvw + 2097152, 1024, 1024);
  tconv_kernel<<<dim3(16, 16), blk, 0, stream>>>(wo, wot, 1024, 1024);
  tconv_kernel<<<dim3(64, 16), blk, 0, stream>>>(w1, w1t, 1024, 4096);
  tconv_kernel<<<dim3(16, 64), blk, 0, stream>>>(w2, w2t, 4096, 1024);

  ln_kernel<<<4096, blk, 0, stream>>>(x, g1, s1, hb);
  gemm_kernel<0><<<dim3(24, 32), blk, 0, stream>>>(hb, qkvw, nullptr, nullptr,
                                                   qbuf, 4096, 3072, 1024);
  attn_kernel<<<dim3(256, 32), dim3(64), 0, stream>>>(
      qbuf, qbuf + 4194304, qbuf + 8388608, pO, pml);
  attn_combine<<<dim3(128, 32), dim3(64), 0, stream>>>(pO, pml, ctxb);
  gemm_kernel<1><<<dim3(8, 32), blk, 0, stream>>>(ctxb, wot, bo, x, x2, 4096,
                                                  1024, 1024);
  ln_kernel<<<4096, blk, 0, stream>>>(x2, g2, s2, h2b);
  gemm_kernel<2><<<dim3(32, 32), blk, 0, stream>>>(h2b, w1t, b1, nullptr, gb,
                                                   4096, 4096, 1024);
  gemm_kernel<1><<<dim3(8, 32), blk, 0, stream>>>(gb, w2t, b2, x2, out, 4096,
                                                  1024, 4096);
}